// Round 1
// baseline (153.423 us; speedup 1.0000x reference)
//
#include <hip/hip_runtime.h>
#include <stdint.h>

#define N_ROWS 4096
#define N_DIM  2048
#define MARGIN 0.3f
#define NTILE  32            // 4096 / 128 tiles per side
#define NITER  (N_DIM / 64)  // BK=64 -> 32 K-iterations
#define FLTMAX 3.402823466e+38f

typedef __attribute__((ext_vector_type(8))) short short8;
typedef __attribute__((ext_vector_type(4))) float floatx4;

// Packed layout ("fragment order"): for 16-row group b (256 total) and k-chunk
// c (32 k, 64 total), a 1 KB block at shorts-offset (b*64+c)*512. Lane l's
// 16 B fragment at l*8 shorts = row b*16+(l&15), k c*32+(l>>4)*8.. (verified
// absmax 0.0 in R1-R7). A BK=64 iter uses k-chunks {2it,2it+1}: contiguous
// 2 KB per row-group.

__device__ inline unsigned short f2bf_rne(float f) {
  unsigned u = __float_as_uint(f);
  unsigned r = 0x7fffu + ((u >> 16) & 1u);
  return (unsigned short)((u + r) >> 16);
}
__device__ inline float bf2f(unsigned short h) {
  return __uint_as_float(((unsigned)h) << 16);
}

// Async global->LDS DMA, 16 B per lane. HW semantics (m104/m108): LDS dest =
// firstlane base + lane*16, which matches the identity chunk map exactly
// (chunk c = q*256 + t -> LDS byte c*16 is linear in lane with stride 16).
__device__ inline void gld_lds16(const unsigned short* g, unsigned short* l) {
  __builtin_amdgcn_global_load_lds(
      (const __attribute__((address_space(1))) void*)g,
      (__attribute__((address_space(3))) void*)l, 16, 0, 0);
}

// ---------------------------------------------------------------------------
// Kernel 1: cast fp32 -> bf16 AND repack into fragment order; sq[i] from the
// ROUNDED values; init per-row reduction cells. One block per 16-row group.
// (Unchanged this round: summation order is part of the absmax=0.0 contract.)
// ---------------------------------------------------------------------------
__global__ __launch_bounds__(256) void prep_kernel(
    const float* __restrict__ X, unsigned short* __restrict__ Xp,
    float* __restrict__ sq, unsigned* __restrict__ ap, unsigned* __restrict__ an)
{
  const int b = blockIdx.x;
  const int t = threadIdx.x;
  const int r = t & 15, j = (t >> 4) & 3, w = t >> 6;
  const float* Xg = X + ((size_t)b * 16 + r) * N_DIM + j * 8;
  unsigned short* Op = Xp + (size_t)b * 64 * 512 + (size_t)(j * 16 + r) * 8;
  float acc = 0.f;
#pragma unroll
  for (int s = 0; s < 16; ++s) {
    const int c = w + s * 4;
    float4 v0 = *(const float4*)(Xg + c * 32);
    float4 v1 = *(const float4*)(Xg + c * 32 + 4);
    short8 o;
    o[0] = (short)f2bf_rne(v0.x); o[1] = (short)f2bf_rne(v0.y);
    o[2] = (short)f2bf_rne(v0.z); o[3] = (short)f2bf_rne(v0.w);
    o[4] = (short)f2bf_rne(v1.x); o[5] = (short)f2bf_rne(v1.y);
    o[6] = (short)f2bf_rne(v1.z); o[7] = (short)f2bf_rne(v1.w);
#pragma unroll
    for (int e = 0; e < 8; ++e) {
      float f = bf2f((unsigned short)o[e]);
      acc = fmaf(f, f, acc);
    }
    *(short8*)(Op + (size_t)c * 512) = o;
  }
  acc += __shfl_xor(acc, 16, 64);
  acc += __shfl_xor(acc, 32, 64);
  __shared__ float part[4][16];
  if ((t & 63) < 16) part[w][r] = acc;
  __syncthreads();
  if (t < 16) {
    float s4 = part[0][t] + part[1][t] + part[2][t] + part[3][t];
    sq[b * 16 + t] = s4;
    ap[b * 16 + t] = 0u;           // max identity (dist >= 0)
    an[b * 16 + t] = 0x7f7fffffu;  // FLT_MAX bits
  }
}

// ---------------------------------------------------------------------------
// Kernel 2: upper-triangle 128x128 tiles, LDS GEMM on the packed array.
// R8: staging via global_load_lds (width=16) — no VGPR round-trip, no vmcnt
// wait before ds_write; the DMA queue drains at the one barrier per iter
// (m97 pattern, m151: +35% vs reg-staging at this tile size). Identity chunk
// map c = q*256 + t keeps both the LDS dest (linear, lane-stride 16 B) and
// the global source (contiguous 1 KB per wave) legal for the DMA. Each
// wave's 64x64 output feeds row-side AND (symmetry) col-side reductions.
// ---------------------------------------------------------------------------
__global__ __launch_bounds__(256, 2) void dist_kernel(
    const unsigned short* __restrict__ Xp, const float* __restrict__ sq,
    const int* __restrict__ lab, unsigned* __restrict__ ap, unsigned* __restrict__ an)
{
  __shared__ __align__(16) unsigned short As[2][8192];   // 2 x 16 KB
  __shared__ __align__(16) unsigned short Bs[2][8192];   // 2 x 16 KB
  __shared__ float sqi[128], sqj[128];
  __shared__ int labi[128], labj[128];

  // decode linear block id -> (bi, bj) with bi <= bj
  int p = blockIdx.x;
  int bi = 0;
  while (p >= NTILE - bi) { p -= NTILE - bi; ++bi; }
  const int bj = bi + p;
  const bool offdiag = (bi != bj);

  const int t = threadIdx.x;
  const int lane = t & 63, w = t >> 6;     // 4 waves
  const int wm = w >> 1, wn = w & 1;       // 2x2 wave grid, 64x64 per wave

  if (t < 128) { int rr = bi * 128 + t; sqi[t] = sq[rr]; labi[t] = lab[rr]; }
  else         { int cc = bj * 128 + (t - 128); sqj[t - 128] = sq[cc]; labj[t - 128] = lab[cc]; }

  // identity chunk map: chunk c = q*256 + t (q = 0..3), 16 B per chunk.
  // LDS shorts offset: c*8. Global shorts offset: ((bX*8 + (c>>7))*64)*512
  // + (c&127)*8, plus it*1024 per K-iter.
  unsigned gA[4], gB[4], lo[4];
#pragma unroll
  for (int q = 0; q < 4; ++q) {
    const unsigned c = q * 256 + t;
    const unsigned seg = c >> 7, off16 = c & 127;
    gA[q] = ((unsigned)(bi * 8 + seg) * 64) * 512 + off16 * 8;
    gB[q] = ((unsigned)(bj * 8 + seg) * 64) * 512 + off16 * 8;
    lo[q] = c * 8;
  }

#define STAGE(BUF, IT)                                                       \
  do {                                                                       \
    _Pragma("unroll")                                                        \
    for (int q = 0; q < 4; ++q) {                                            \
      gld_lds16(Xp + gA[q] + (unsigned)(IT) * 1024u, &As[BUF][lo[q]]);       \
      if (offdiag)                                                           \
        gld_lds16(Xp + gB[q] + (unsigned)(IT) * 1024u, &Bs[BUF][lo[q]]);     \
    }                                                                        \
  } while (0)

  STAGE(0, 0);
  __syncthreads();                         // tile 0 DMA drained + sqi/sqj visible

  floatx4 acc[4][4] = {};

  for (int it = 0; it < NITER; ++it) {
    const int cur = it & 1;
    if (it + 1 < NITER) STAGE(cur ^ 1, it + 1);  // async DMA, overlaps compute

    const unsigned short* Asrc = As[cur];
    const unsigned short* Bsrc = offdiag ? Bs[cur] : As[cur];
#pragma unroll
    for (int kh = 0; kh < 2; ++kh) {
      short8 af[4], bfv[4];
#pragma unroll
      for (int mi = 0; mi < 4; ++mi)
        af[mi] = *(const short8*)&Asrc[((wm * 4 + mi) * 2 + kh) * 512 + lane * 8];
#pragma unroll
      for (int ni = 0; ni < 4; ++ni)
        bfv[ni] = *(const short8*)&Bsrc[((wn * 4 + ni) * 2 + kh) * 512 + lane * 8];
#pragma unroll
      for (int mi = 0; mi < 4; ++mi)
#pragma unroll
        for (int ni = 0; ni < 4; ++ni)
          acc[mi][ni] = __builtin_amdgcn_mfma_f32_16x16x32_bf16(
              af[mi], bfv[ni], acc[mi][ni], 0, 0, 0);
    }

    // one barrier per iter: drains this iter's DMA (next buffer ready) and
    // orders this iter's ds_reads before next iter's DMA overwrites them.
    __syncthreads();
  }
#undef STAGE

  // Epilogue. C/D layout (m89): col = lane&15, row = (lane>>4)*4 + reg.
  const int cn = lane & 15, lg = lane >> 4;
  float sqc[4]; int labc[4];
#pragma unroll
  for (int ni = 0; ni < 4; ++ni) {
    int c = wn * 64 + ni * 16 + cn;
    sqc[ni] = sqj[c]; labc[ni] = labj[c];
  }
  float cap[4] = {0.f, 0.f, 0.f, 0.f};
  float can[4] = {FLTMAX, FLTMAX, FLTMAX, FLTMAX};
#pragma unroll
  for (int mi = 0; mi < 4; ++mi) {
#pragma unroll
    for (int r = 0; r < 4; ++r) {
      const int rl = wm * 64 + mi * 16 + lg * 4 + r;   // row within 128-tile
      const float si = sqi[rl];
      const int li = labi[rl];
      float apv = 0.0f;
      float anv = FLTMAX;
#pragma unroll
      for (int ni = 0; ni < 4; ++ni) {
        float g = acc[mi][ni][r];
        float d2 = fmaf(-2.0f, g, si + sqc[ni]);
        d2 = fmaxf(d2, 1e-12f);
        float d = __builtin_amdgcn_sqrtf(d2);
        const bool same = (li == labc[ni]);
        const float dp = same ? d : 0.0f;
        const float dn = same ? FLTMAX : d;
        apv = fmaxf(apv, dp);
        anv = fminf(anv, dn);
        cap[ni] = fmaxf(cap[ni], dp);   // col-side (symmetric) partials
        can[ni] = fminf(can[ni], dn);
      }
      // row side: reduce over the 16 cn-lanes (same lg = same row)
#pragma unroll
      for (int m = 8; m >= 1; m >>= 1) {
        apv = fmaxf(apv, __shfl_xor(apv, m, 64));
        anv = fminf(anv, __shfl_xor(anv, m, 64));
      }
      if (cn == 0) {
        int R = bi * 128 + rl;
        atomicMax(&ap[R], __float_as_uint(apv));
        atomicMin(&an[R], __float_as_uint(anv));
      }
    }
  }
  // col side: reduce over lg (xor 16,32) -> full 64 rows per column
#pragma unroll
  for (int ni = 0; ni < 4; ++ni) {
    float a = cap[ni], b = can[ni];
#pragma unroll
    for (int m = 16; m <= 32; m <<= 1) {
      a = fmaxf(a, __shfl_xor(a, m, 64));
      b = fminf(b, __shfl_xor(b, m, 64));
    }
    if (lg == 0) {
      int C = bj * 128 + wn * 64 + ni * 16 + cn;
      atomicMax(&ap[C], __float_as_uint(a));
      atomicMin(&an[C], __float_as_uint(b));
    }
  }
}

// ---------------------------------------------------------------------------
// Kernel 3: loss = mean(relu(margin + dist_ap - dist_an))
// ---------------------------------------------------------------------------
__global__ __launch_bounds__(256) void finalize_kernel(
    const unsigned* __restrict__ ap, const unsigned* __restrict__ an,
    float* __restrict__ out)
{
  const int t = threadIdx.x;
  float s = 0.f;
  for (int i = t; i < N_ROWS; i += 256) {
    float a = __uint_as_float(ap[i]);
    float b = __uint_as_float(an[i]);
    s += fmaxf(MARGIN + a - b, 0.0f);
  }
#pragma unroll
  for (int m = 32; m >= 1; m >>= 1) s += __shfl_down(s, m, 64);
  __shared__ float wsum[4];
  const int lane = t & 63, w = t >> 6;
  if (lane == 0) wsum[w] = s;
  __syncthreads();
  if (t == 0) out[0] = (wsum[0] + wsum[1] + wsum[2] + wsum[3]) * (1.0f / N_ROWS);
}

extern "C" void kernel_launch(void* const* d_in, const int* in_sizes, int n_in,
                              void* d_out, int out_size, void* d_ws, size_t ws_size,
                              hipStream_t stream) {
  const float* X = (const float*)d_in[0];
  const int* lab = (const int*)d_in[1];
  float* out = (float*)d_out;

  char* ws = (char*)d_ws;
  unsigned short* Xp = (unsigned short*)ws;                           // 16 MB packed
  float* sq  = (float*)(ws + (size_t)N_ROWS * N_DIM * 2);             // 16 KB
  unsigned* ap = (unsigned*)((char*)sq + N_ROWS * sizeof(float));     // 16 KB
  unsigned* an = (unsigned*)((char*)ap + N_ROWS * sizeof(unsigned));  // 16 KB

  prep_kernel<<<N_ROWS / 16, 256, 0, stream>>>(X, Xp, sq, ap, an);
  dist_kernel<<<NTILE * (NTILE + 1) / 2, 256, 0, stream>>>(Xp, sq, lab, ap, an);
  finalize_kernel<<<1, 256, 0, stream>>>(ap, an, out);
}

// Round 2
// 145.353 us; speedup vs baseline: 1.0555x; 1.0555x over previous
//
#include <hip/hip_runtime.h>
#include <stdint.h>

#define N_ROWS 4096
#define N_DIM  2048
#define MARGIN 0.3f
#define NITER  (N_DIM / 64)  // BK=64 -> 32 K-iterations
#define FLTMAX 3.402823466e+38f

// R2 tiling: 64 (A-rows) x 128 (B-cols) tiles. bi in [0,64), bj in [0,32),
// keep tiles with bj >= bi/2 (any upper-triangle cell) -> 1056 blocks
// (4.125/CU; single-buffer 25.5KB LDS -> capacity 6 -> all co-resident).
#define NBI 64
#define NBJ 32
#define NBLOCKS 1056         // sum_{bi=0}^{63} (32 - bi/2)

typedef __attribute__((ext_vector_type(8))) short short8;
typedef __attribute__((ext_vector_type(4))) float floatx4;

// Packed layout ("fragment order"): for 16-row group g (256 total) and k-chunk
// c (32 k each, 64 total), a 1 KB block at shorts-offset (g*64+c)*512. Lane l's
// 16 B fragment at l*8 shorts = row g*16+(l&15), k c*32+(l>>4)*8.. (verified
// absmax 0.0). A BK=64 iter uses k-chunks {2it,2it+1}: contiguous 2 KB per
// row-group.

__device__ inline unsigned short f2bf_rne(float f) {
  unsigned u = __float_as_uint(f);
  unsigned r = 0x7fffu + ((u >> 16) & 1u);
  return (unsigned short)((u + r) >> 16);
}
__device__ inline float bf2f(unsigned short h) {
  return __uint_as_float(((unsigned)h) << 16);
}

// Async global->LDS DMA, 16 B per lane. LDS dest = firstlane base + lane*16,
// which the identity chunk map satisfies (u = q*256 + t -> LDS byte u*16).
__device__ inline void gld_lds16(const unsigned short* g, unsigned short* l) {
  __builtin_amdgcn_global_load_lds(
      (const __attribute__((address_space(1))) void*)g,
      (__attribute__((address_space(3))) void*)l, 16, 0, 0);
}

// ---------------------------------------------------------------------------
// Kernel 1: cast fp32 -> bf16 AND repack into fragment order; sq[i] from the
// ROUNDED values; init per-row reduction cells. One block per 16-row group.
// (Unchanged: summation order is part of the absmax=0.0 contract.)
// ---------------------------------------------------------------------------
__global__ __launch_bounds__(256) void prep_kernel(
    const float* __restrict__ X, unsigned short* __restrict__ Xp,
    float* __restrict__ sq, unsigned* __restrict__ ap, unsigned* __restrict__ an)
{
  const int b = blockIdx.x;
  const int t = threadIdx.x;
  const int r = t & 15, j = (t >> 4) & 3, w = t >> 6;
  const float* Xg = X + ((size_t)b * 16 + r) * N_DIM + j * 8;
  unsigned short* Op = Xp + (size_t)b * 64 * 512 + (size_t)(j * 16 + r) * 8;
  float acc = 0.f;
#pragma unroll
  for (int s = 0; s < 16; ++s) {
    const int c = w + s * 4;
    float4 v0 = *(const float4*)(Xg + c * 32);
    float4 v1 = *(const float4*)(Xg + c * 32 + 4);
    short8 o;
    o[0] = (short)f2bf_rne(v0.x); o[1] = (short)f2bf_rne(v0.y);
    o[2] = (short)f2bf_rne(v0.z); o[3] = (short)f2bf_rne(v0.w);
    o[4] = (short)f2bf_rne(v1.x); o[5] = (short)f2bf_rne(v1.y);
    o[6] = (short)f2bf_rne(v1.z); o[7] = (short)f2bf_rne(v1.w);
#pragma unroll
    for (int e = 0; e < 8; ++e) {
      float f = bf2f((unsigned short)o[e]);
      acc = fmaf(f, f, acc);
    }
    *(short8*)(Op + (size_t)c * 512) = o;
  }
  acc += __shfl_xor(acc, 16, 64);
  acc += __shfl_xor(acc, 32, 64);
  __shared__ float part[4][16];
  if ((t & 63) < 16) part[w][r] = acc;
  __syncthreads();
  if (t < 16) {
    float s4 = part[0][t] + part[1][t] + part[2][t] + part[3][t];
    sq[b * 16 + t] = s4;
    ap[b * 16 + t] = 0u;           // max identity (dist >= 0)
    an[b * 16 + t] = 0x7f7fffffu;  // FLT_MAX bits
  }
}

// ---------------------------------------------------------------------------
// Kernel 2: 64x128 tiles, single-buffered LDS, gld_lds staging, m97-style
// 2-barrier K-loop. 4 waves (2x2 wave grid, 32x64 output each, acc[2][4]).
// Max/min reductions tolerate duplicate coverage, so straddle tiles compute
// the full rectangle; every (i<=j) pair is covered as (i,j) row-side, every
// (i>j) via the col-side of tile (j,i). Per-cell K-accumulation order is
// identical to R0 (same MFMA chain) -> bit-identical d2.
// ---------------------------------------------------------------------------
__global__ __launch_bounds__(256, 4) void dist_kernel(
    const unsigned short* __restrict__ Xp, const float* __restrict__ sq,
    const int* __restrict__ lab, unsigned* __restrict__ ap, unsigned* __restrict__ an)
{
  __shared__ __align__(16) unsigned short As[4096];   // 8 KB  (64 rows x 64 k)
  __shared__ __align__(16) unsigned short Bs[8192];   // 16 KB (128 rows x 64 k)
  __shared__ float sqi[64], sqj[128];
  __shared__ int labi[64], labj[128];

  // decode linear block id -> (bi, bj) with bj >= bi/2
  int p = blockIdx.x;
  int bi = 0;
  while (p >= NBJ - (bi >> 1)) { p -= NBJ - (bi >> 1); ++bi; }
  const int bj = (bi >> 1) + p;

  const int t = threadIdx.x;
  const int lane = t & 63, w = t >> 6;     // 4 waves
  const int wm = w >> 1, wn = w & 1;       // 2x2 wave grid: 32 rows x 64 cols

  if (t < 64)       { int rr = bi * 64 + t;        sqi[t] = sq[rr];        labi[t] = lab[rr]; }
  else if (t < 192) { int cc = bj * 128 + (t - 64); sqj[t - 64] = sq[cc];  labj[t - 64] = lab[cc]; }

  // identity chunk map, 16 B units. A: 512 units (2/thread), B: 1024 (4/thread).
  // unit u: group gg = u>>7 (A: bi*4+gg, B: bj*8+gg), within-2KB off = u&127.
  // Wave-uniform gg and lane-contiguous off/LDS: legal for gld_lds.
  unsigned gA[2], gB[4], loA[2], loB[4];
#pragma unroll
  for (int q = 0; q < 2; ++q) {
    const unsigned u = q * 256 + t;
    gA[q] = ((unsigned)(bi * 4 + (u >> 7)) * 64) * 512 + (u & 127) * 8;
    loA[q] = u * 8;
  }
#pragma unroll
  for (int q = 0; q < 4; ++q) {
    const unsigned u = q * 256 + t;
    gB[q] = ((unsigned)(bj * 8 + (u >> 7)) * 64) * 512 + (u & 127) * 8;
    loB[q] = u * 8;
  }

  floatx4 acc[2][4] = {};

  for (int it = 0; it < NITER; ++it) {
    const unsigned koff = (unsigned)it * 1024u;   // 2 k-chunks = 1024 shorts
#pragma unroll
    for (int q = 0; q < 2; ++q) gld_lds16(Xp + gA[q] + koff, &As[loA[q]]);
#pragma unroll
    for (int q = 0; q < 4; ++q) gld_lds16(Xp + gB[q] + koff, &Bs[loB[q]]);
    __syncthreads();                       // DMA drained + visible

#pragma unroll
    for (int kh = 0; kh < 2; ++kh) {
      short8 af[2], bfv[4];
#pragma unroll
      for (int mi = 0; mi < 2; ++mi)
        af[mi] = *(const short8*)&As[((wm * 2 + mi) * 2 + kh) * 512 + lane * 8];
#pragma unroll
      for (int ni = 0; ni < 4; ++ni)
        bfv[ni] = *(const short8*)&Bs[((wn * 4 + ni) * 2 + kh) * 512 + lane * 8];
#pragma unroll
      for (int mi = 0; mi < 2; ++mi)
#pragma unroll
        for (int ni = 0; ni < 4; ++ni)
          acc[mi][ni] = __builtin_amdgcn_mfma_f32_16x16x32_bf16(
              af[mi], bfv[ni], acc[mi][ni], 0, 0, 0);
    }
    __syncthreads();                       // reads done before next stage
  }

  // Epilogue. C/D layout (m89): col = lane&15, row = (lane>>4)*4 + reg.
  const int cn = lane & 15, lg = lane >> 4;
  float sqc[4]; int labc[4];
#pragma unroll
  for (int ni = 0; ni < 4; ++ni) {
    int c = wn * 64 + ni * 16 + cn;
    sqc[ni] = sqj[c]; labc[ni] = labj[c];
  }
  float cap[4] = {0.f, 0.f, 0.f, 0.f};
  float can[4] = {FLTMAX, FLTMAX, FLTMAX, FLTMAX};
#pragma unroll
  for (int mi = 0; mi < 2; ++mi) {
#pragma unroll
    for (int r = 0; r < 4; ++r) {
      const int rl = wm * 32 + mi * 16 + lg * 4 + r;   // row within 64-tile
      const float si = sqi[rl];
      const int li = labi[rl];
      float apv = 0.0f;
      float anv = FLTMAX;
#pragma unroll
      for (int ni = 0; ni < 4; ++ni) {
        float g = acc[mi][ni][r];
        float d2 = fmaf(-2.0f, g, si + sqc[ni]);
        d2 = fmaxf(d2, 1e-12f);
        float d = __builtin_amdgcn_sqrtf(d2);
        const bool same = (li == labc[ni]);
        const float dp = same ? d : 0.0f;
        const float dn = same ? FLTMAX : d;
        apv = fmaxf(apv, dp);
        anv = fminf(anv, dn);
        cap[ni] = fmaxf(cap[ni], dp);   // col-side (symmetric) partials
        can[ni] = fminf(can[ni], dn);
      }
      // row side: reduce over the 16 cn-lanes (same lg = same row)
#pragma unroll
      for (int m = 8; m >= 1; m >>= 1) {
        apv = fmaxf(apv, __shfl_xor(apv, m, 64));
        anv = fminf(anv, __shfl_xor(anv, m, 64));
      }
      if (cn == 0) {
        int R = bi * 64 + rl;
        atomicMax(&ap[R], __float_as_uint(apv));
        atomicMin(&an[R], __float_as_uint(anv));
      }
    }
  }
  // col side: reduce over lg (xor 16,32) -> full 64 rows per column
#pragma unroll
  for (int ni = 0; ni < 4; ++ni) {
    float a = cap[ni], b = can[ni];
#pragma unroll
    for (int m = 16; m <= 32; m <<= 1) {
      a = fmaxf(a, __shfl_xor(a, m, 64));
      b = fminf(b, __shfl_xor(b, m, 64));
    }
    if (lg == 0) {
      int C = bj * 128 + wn * 64 + ni * 16 + cn;
      atomicMax(&ap[C], __float_as_uint(a));
      atomicMin(&an[C], __float_as_uint(b));
    }
  }
}

// ---------------------------------------------------------------------------
// Kernel 3: loss = mean(relu(margin + dist_ap - dist_an))
// ---------------------------------------------------------------------------
__global__ __launch_bounds__(256) void finalize_kernel(
    const unsigned* __restrict__ ap, const unsigned* __restrict__ an,
    float* __restrict__ out)
{
  const int t = threadIdx.x;
  float s = 0.f;
  for (int i = t; i < N_ROWS; i += 256) {
    float a = __uint_as_float(ap[i]);
    float b = __uint_as_float(an[i]);
    s += fmaxf(MARGIN + a - b, 0.0f);
  }
#pragma unroll
  for (int m = 32; m >= 1; m >>= 1) s += __shfl_down(s, m, 64);
  __shared__ float wsum[4];
  const int lane = t & 63, w = t >> 6;
  if (lane == 0) wsum[w] = s;
  __syncthreads();
  if (t == 0) out[0] = (wsum[0] + wsum[1] + wsum[2] + wsum[3]) * (1.0f / N_ROWS);
}

extern "C" void kernel_launch(void* const* d_in, const int* in_sizes, int n_in,
                              void* d_out, int out_size, void* d_ws, size_t ws_size,
                              hipStream_t stream) {
  const float* X = (const float*)d_in[0];
  const int* lab = (const int*)d_in[1];
  float* out = (float*)d_out;

  char* ws = (char*)d_ws;
  unsigned short* Xp = (unsigned short*)ws;                           // 16 MB packed
  float* sq  = (float*)(ws + (size_t)N_ROWS * N_DIM * 2);             // 16 KB
  unsigned* ap = (unsigned*)((char*)sq + N_ROWS * sizeof(float));     // 16 KB
  unsigned* an = (unsigned*)((char*)ap + N_ROWS * sizeof(unsigned));  // 16 KB

  prep_kernel<<<N_ROWS / 16, 256, 0, stream>>>(X, Xp, sq, ap, an);
  dist_kernel<<<NBLOCKS, 256, 0, stream>>>(Xp, sq, lab, ap, an);
  finalize_kernel<<<1, 256, 0, stream>>>(ap, an, out);
}

// Round 3
// 138.768 us; speedup vs baseline: 1.1056x; 1.0475x over previous
//
#include <hip/hip_runtime.h>
#include <stdint.h>

#define N_ROWS 4096
#define N_DIM  2048
#define MARGIN 0.3f
#define NITER  (N_DIM / 64)  // BK=64 -> 32 K-iterations
#define FLTMAX 3.402823466e+38f

// Tiling: 64 (A-rows) x 128 (B-cols) tiles. bi in [0,64), bj in [0,32),
// keep tiles with bj >= bi/2 (covers all upper-triangle cells) -> 1056 blocks
// (4.125/CU, balanced).
#define NBI 64
#define NBJ 32
#define NBLOCKS 1056         // sum_{bi=0}^{63} (32 - bi/2)

typedef __attribute__((ext_vector_type(8))) short short8;
typedef __attribute__((ext_vector_type(4))) float floatx4;

// Packed layout ("fragment order"): for 16-row group g (256 total) and k-chunk
// c (32 k each, 64 total), a 1 KB block at shorts-offset (g*64+c)*512. Lane l's
// 16 B fragment at l*8 shorts = row g*16+(l&15), k c*32+(l>>4)*8.. (verified
// absmax 0.0). A BK=64 iter uses k-chunks {2it,2it+1}: contiguous 2 KB per
// row-group.

__device__ inline unsigned short f2bf_rne(float f) {
  unsigned u = __float_as_uint(f);
  unsigned r = 0x7fffu + ((u >> 16) & 1u);
  return (unsigned short)((u + r) >> 16);
}
__device__ inline float bf2f(unsigned short h) {
  return __uint_as_float(((unsigned)h) << 16);
}

// Async global->LDS DMA, 16 B per lane. LDS dest = firstlane base + lane*16,
// which the identity chunk map satisfies (u = q*256 + t -> LDS byte u*16).
__device__ inline void gld_lds16(const unsigned short* g, unsigned short* l) {
  __builtin_amdgcn_global_load_lds(
      (const __attribute__((address_space(1))) void*)g,
      (__attribute__((address_space(3))) void*)l, 16, 0, 0);
}

// ---------------------------------------------------------------------------
// Kernel 1: cast fp32 -> bf16 AND repack into fragment order; sq[i] from the
// ROUNDED values; init per-row reduction cells. One block per 16-row group.
// R3: all 32 float4 loads hoisted ahead of the compute loop (grid = 1
// block/CU = 1 wave/SIMD, so latency must be hidden by MLP, not TLP; VGPRs
// are free at this occupancy). fmaf chain order and store values unchanged
// -> sq bit-identical (absmax=0.0 contract).
// ---------------------------------------------------------------------------
__global__ __launch_bounds__(256) void prep_kernel(
    const float* __restrict__ X, unsigned short* __restrict__ Xp,
    float* __restrict__ sq, unsigned* __restrict__ ap, unsigned* __restrict__ an)
{
  const int b = blockIdx.x;
  const int t = threadIdx.x;
  const int r = t & 15, j = (t >> 4) & 3, w = t >> 6;
  const float* Xg = X + ((size_t)b * 16 + r) * N_DIM + j * 8;
  unsigned short* Op = Xp + (size_t)b * 64 * 512 + (size_t)(j * 16 + r) * 8;

  float4 v[16][2];
#pragma unroll
  for (int s = 0; s < 16; ++s) {
    const int c = w + s * 4;
    v[s][0] = *(const float4*)(Xg + c * 32);
    v[s][1] = *(const float4*)(Xg + c * 32 + 4);
  }

  float acc = 0.f;
#pragma unroll
  for (int s = 0; s < 16; ++s) {
    const int c = w + s * 4;
    short8 o;
    o[0] = (short)f2bf_rne(v[s][0].x); o[1] = (short)f2bf_rne(v[s][0].y);
    o[2] = (short)f2bf_rne(v[s][0].z); o[3] = (short)f2bf_rne(v[s][0].w);
    o[4] = (short)f2bf_rne(v[s][1].x); o[5] = (short)f2bf_rne(v[s][1].y);
    o[6] = (short)f2bf_rne(v[s][1].z); o[7] = (short)f2bf_rne(v[s][1].w);
#pragma unroll
    for (int e = 0; e < 8; ++e) {
      float f = bf2f((unsigned short)o[e]);
      acc = fmaf(f, f, acc);
    }
    *(short8*)(Op + (size_t)c * 512) = o;
  }
  acc += __shfl_xor(acc, 16, 64);
  acc += __shfl_xor(acc, 32, 64);
  __shared__ float part[4][16];
  if ((t & 63) < 16) part[w][r] = acc;
  __syncthreads();
  if (t < 16) {
    float s4 = part[0][t] + part[1][t] + part[2][t] + part[3][t];
    sq[b * 16 + t] = s4;
    ap[b * 16 + t] = 0u;           // max identity (dist >= 0)
    an[b * 16 + t] = 0x7f7fffffu;  // FLT_MAX bits
  }
}

// ---------------------------------------------------------------------------
// Kernel 2, R3: 64x128 tiles, 1x4 wave grid (each wave: 64 rows x 32 cols,
// acc[4][2]). A staged in LDS via gld_lds (shared 4x by all waves, double-
// buffered 2x8KB, ONE barrier/iter = T3 minimum 2-phase). B columns are
// disjoint per wave -> loaded DIRECT from the packed array into registers
// (per-lane contiguous 16 B = the exact MFMA fragment), prefetched one iter
// ahead. LDS traffic drops from 72 KB to 40 KB per block-iter (-45%); global
// volume unchanged (L2/L3-resident). Per-cell MFMA chain identical to R2
// (it ascending, kh 0/1, same fragment data) -> bit-identical d2.
// ---------------------------------------------------------------------------
__global__ __launch_bounds__(256, 4) void dist_kernel(
    const unsigned short* __restrict__ Xp, const float* __restrict__ sq,
    const int* __restrict__ lab, unsigned* __restrict__ ap, unsigned* __restrict__ an)
{
  __shared__ __align__(16) unsigned short As[2][4096];   // 2 x 8 KB (64 rows x 64 k)
  __shared__ float sqi[64], sqj[128];
  __shared__ int labi[64], labj[128];

  // decode linear block id -> (bi, bj) with bj >= bi/2
  int p = blockIdx.x;
  int bi = 0;
  while (p >= NBJ - (bi >> 1)) { p -= NBJ - (bi >> 1); ++bi; }
  const int bj = (bi >> 1) + p;

  const int t = threadIdx.x;
  const int lane = t & 63, w = t >> 6;     // 4 waves, 1x4 grid: wave w owns
                                           // cols [w*32, w*32+32), all 64 rows

  if (t < 64)       { int rr = bi * 64 + t;         sqi[t] = sq[rr];        labi[t] = lab[rr]; }
  else if (t < 192) { int cc = bj * 128 + (t - 64); sqj[t - 64] = sq[cc];   labj[t - 64] = lab[cc]; }

  // A staging: identity chunk map, 512 x 16B units (2/thread). unit u: group
  // gg = u>>7 (wave-uniform), off = u&127 (lane-contiguous) -> legal gld_lds.
  unsigned gA[2], loA[2];
#pragma unroll
  for (int q = 0; q < 2; ++q) {
    const unsigned u = q * 256 + t;
    gA[q] = ((unsigned)(bi * 4 + (u >> 7)) * 64) * 512 + (u & 127) * 8;
    loA[q] = u * 8;
  }
  // B direct: wave w's col 16-groups are (w*2) and (w*2+1). Fragment for
  // (ni, it, kh) at Bb[ni] + it*1024 + kh*512 (shorts), per-lane 16 B.
  const unsigned short* Bb[2];
#pragma unroll
  for (int ni = 0; ni < 2; ++ni)
    Bb[ni] = Xp + ((size_t)(unsigned)(bj * 8 + w * 2 + ni) * 64) * 512 + (unsigned)lane * 8;

#define STAGE_A(BUF, IT)                                                     \
  do {                                                                       \
    _Pragma("unroll")                                                        \
    for (int q = 0; q < 2; ++q)                                              \
      gld_lds16(Xp + gA[q] + (unsigned)(IT) * 1024u, &As[BUF][loA[q]]);      \
  } while (0)

  short8 bc[2][2], bn[2][2];
  STAGE_A(0, 0);
#pragma unroll
  for (int ni = 0; ni < 2; ++ni)
#pragma unroll
    for (int kh = 0; kh < 2; ++kh)
      bc[ni][kh] = *(const short8*)(Bb[ni] + kh * 512);
  __syncthreads();                         // A(0) drained + sqi/sqj visible

  floatx4 acc[4][2] = {};

  for (int it = 0; it < NITER; ++it) {
    const int cur = it & 1;
    const bool has_next = (it + 1 < NITER);
    if (has_next) {
      STAGE_A(cur ^ 1, it + 1);            // async DMA into other buffer
#pragma unroll
      for (int ni = 0; ni < 2; ++ni)
#pragma unroll
        for (int kh = 0; kh < 2; ++kh)
          bn[ni][kh] = *(const short8*)(Bb[ni] + (unsigned)(it + 1) * 1024u + kh * 512);
    }

#pragma unroll
    for (int kh = 0; kh < 2; ++kh) {
      short8 af[4];
#pragma unroll
      for (int mi = 0; mi < 4; ++mi)
        af[mi] = *(const short8*)&As[cur][(mi * 2 + kh) * 512 + lane * 8];
#pragma unroll
      for (int mi = 0; mi < 4; ++mi)
#pragma unroll
        for (int ni = 0; ni < 2; ++ni)
          acc[mi][ni] = __builtin_amdgcn_mfma_f32_16x16x32_bf16(
              af[mi], bc[ni][kh], acc[mi][ni], 0, 0, 0);
    }

    // ONE barrier per iter: all waves' As[cur] reads done (safe to overwrite
    // next iter) AND the implicit vmcnt(0) drains the DMA into As[cur^1].
    __syncthreads();
    if (has_next) {
#pragma unroll
      for (int ni = 0; ni < 2; ++ni)
#pragma unroll
        for (int kh = 0; kh < 2; ++kh)
          bc[ni][kh] = bn[ni][kh];
    }
  }
#undef STAGE_A

  // Epilogue. C/D layout (m89): col = lane&15, row = (lane>>4)*4 + reg.
  const int cn = lane & 15, lg = lane >> 4;
  float sqc[2]; int labc[2];
#pragma unroll
  for (int ni = 0; ni < 2; ++ni) {
    int c = w * 32 + ni * 16 + cn;
    sqc[ni] = sqj[c]; labc[ni] = labj[c];
  }
  float cap[2] = {0.f, 0.f};
  float can[2] = {FLTMAX, FLTMAX};
#pragma unroll
  for (int mi = 0; mi < 4; ++mi) {
#pragma unroll
    for (int r = 0; r < 4; ++r) {
      const int rl = mi * 16 + lg * 4 + r;   // row within 64-tile
      const float si = sqi[rl];
      const int li = labi[rl];
      float apv = 0.0f;
      float anv = FLTMAX;
#pragma unroll
      for (int ni = 0; ni < 2; ++ni) {
        float g = acc[mi][ni][r];
        float d2 = fmaf(-2.0f, g, si + sqc[ni]);
        d2 = fmaxf(d2, 1e-12f);
        float d = __builtin_amdgcn_sqrtf(d2);
        const bool same = (li == labc[ni]);
        const float dp = same ? d : 0.0f;
        const float dn = same ? FLTMAX : d;
        apv = fmaxf(apv, dp);
        anv = fminf(anv, dn);
        cap[ni] = fmaxf(cap[ni], dp);   // col-side (symmetric) partials
        can[ni] = fminf(can[ni], dn);
      }
      // row side: reduce over the 16 cn-lanes (same lg = same row)
#pragma unroll
      for (int m = 8; m >= 1; m >>= 1) {
        apv = fmaxf(apv, __shfl_xor(apv, m, 64));
        anv = fminf(anv, __shfl_xor(anv, m, 64));
      }
      if (cn == 0) {
        int R = bi * 64 + rl;
        atomicMax(&ap[R], __float_as_uint(apv));
        atomicMin(&an[R], __float_as_uint(anv));
      }
    }
  }
  // col side: reduce over lg (xor 16,32) -> full 64 rows per column
#pragma unroll
  for (int ni = 0; ni < 2; ++ni) {
    float a = cap[ni], b = can[ni];
#pragma unroll
    for (int m = 16; m <= 32; m <<= 1) {
      a = fmaxf(a, __shfl_xor(a, m, 64));
      b = fminf(b, __shfl_xor(b, m, 64));
    }
    if (lg == 0) {
      int C = bj * 128 + w * 32 + ni * 16 + cn;
      atomicMax(&ap[C], __float_as_uint(a));
      atomicMin(&an[C], __float_as_uint(b));
    }
  }
}

// ---------------------------------------------------------------------------
// Kernel 3: loss = mean(relu(margin + dist_ap - dist_an))
// ---------------------------------------------------------------------------
__global__ __launch_bounds__(256) void finalize_kernel(
    const unsigned* __restrict__ ap, const unsigned* __restrict__ an,
    float* __restrict__ out)
{
  const int t = threadIdx.x;
  float s = 0.f;
  for (int i = t; i < N_ROWS; i += 256) {
    float a = __uint_as_float(ap[i]);
    float b = __uint_as_float(an[i]);
    s += fmaxf(MARGIN + a - b, 0.0f);
  }
#pragma unroll
  for (int m = 32; m >= 1; m >>= 1) s += __shfl_down(s, m, 64);
  __shared__ float wsum[4];
  const int lane = t & 63, w = t >> 6;
  if (lane == 0) wsum[w] = s;
  __syncthreads();
  if (t == 0) out[0] = (wsum[0] + wsum[1] + wsum[2] + wsum[3]) * (1.0f / N_ROWS);
}

extern "C" void kernel_launch(void* const* d_in, const int* in_sizes, int n_in,
                              void* d_out, int out_size, void* d_ws, size_t ws_size,
                              hipStream_t stream) {
  const float* X = (const float*)d_in[0];
  const int* lab = (const int*)d_in[1];
  float* out = (float*)d_out;

  char* ws = (char*)d_ws;
  unsigned short* Xp = (unsigned short*)ws;                           // 16 MB packed
  float* sq  = (float*)(ws + (size_t)N_ROWS * N_DIM * 2);             // 16 KB
  unsigned* ap = (unsigned*)((char*)sq + N_ROWS * sizeof(float));     // 16 KB
  unsigned* an = (unsigned*)((char*)ap + N_ROWS * sizeof(unsigned));  // 16 KB

  prep_kernel<<<N_ROWS / 16, 256, 0, stream>>>(X, Xp, sq, ap, an);
  dist_kernel<<<NBLOCKS, 256, 0, stream>>>(Xp, sq, lab, ap, an);
  finalize_kernel<<<1, 256, 0, stream>>>(ap, an, out);
}

// Round 4
// 135.420 us; speedup vs baseline: 1.1329x; 1.0247x over previous
//
#include <hip/hip_runtime.h>
#include <stdint.h>

#define N_ROWS 4096
#define N_DIM  2048
#define MARGIN 0.3f
#define NITER  (N_DIM / 64)  // BK=64 -> 32 K-iterations
#define FLTMAX 3.402823466e+38f

// Tiling: 64 (A-rows) x 128 (B-cols) tiles. bi in [0,64), bj in [0,32),
// keep tiles with bj >= bi/2 (covers all upper-triangle cells) -> 1056 blocks
// (4.125/CU, balanced).
#define NBI 64
#define NBJ 32
#define NBLOCKS 1056         // sum_{bi=0}^{63} (32 - bi/2)

typedef __attribute__((ext_vector_type(8))) short short8;
typedef __attribute__((ext_vector_type(4))) float floatx4;

// Packed layout ("fragment order"): for 16-row group g (256 total) and k-chunk
// c (32 k each, 64 total), a 1 KB block at shorts-offset (g*64+c)*512. Lane l's
// 16 B fragment at l*8 shorts = row g*16+(l&15), k c*32+(l>>4)*8.. (verified
// absmax 0.0). A BK=64 iter uses k-chunks {2it,2it+1}: contiguous 2 KB per
// row-group.

__device__ inline unsigned short f2bf_rne(float f) {
  unsigned u = __float_as_uint(f);
  unsigned r = 0x7fffu + ((u >> 16) & 1u);
  return (unsigned short)((u + r) >> 16);
}
__device__ inline float bf2f(unsigned short h) {
  return __uint_as_float(((unsigned)h) << 16);
}

// Async global->LDS DMA, 16 B per lane. LDS dest = firstlane base + lane*16.
__device__ inline void gld_lds16(const void* g, void* l) {
  __builtin_amdgcn_global_load_lds(
      (const __attribute__((address_space(1))) void*)g,
      (__attribute__((address_space(3))) void*)l, 16, 0, 0);
}

// Counted vmcnt wait (even N, 0..30). Called with a compile-time constant in
// unrolled loops -> folds to a single asm. "memory" clobber keeps loads/reads
// from hoisting above; callers add sched_barrier(0) to pin scheduling.
__device__ inline void wait_vmcnt_even(int n) {
  switch (n) {
    case 0:  asm volatile("s_waitcnt vmcnt(0)" ::: "memory"); break;
    case 2:  asm volatile("s_waitcnt vmcnt(2)" ::: "memory"); break;
    case 4:  asm volatile("s_waitcnt vmcnt(4)" ::: "memory"); break;
    case 6:  asm volatile("s_waitcnt vmcnt(6)" ::: "memory"); break;
    case 8:  asm volatile("s_waitcnt vmcnt(8)" ::: "memory"); break;
    case 10: asm volatile("s_waitcnt vmcnt(10)" ::: "memory"); break;
    case 12: asm volatile("s_waitcnt vmcnt(12)" ::: "memory"); break;
    case 14: asm volatile("s_waitcnt vmcnt(14)" ::: "memory"); break;
    case 16: asm volatile("s_waitcnt vmcnt(16)" ::: "memory"); break;
    case 18: asm volatile("s_waitcnt vmcnt(18)" ::: "memory"); break;
    case 20: asm volatile("s_waitcnt vmcnt(20)" ::: "memory"); break;
    case 22: asm volatile("s_waitcnt vmcnt(22)" ::: "memory"); break;
    case 24: asm volatile("s_waitcnt vmcnt(24)" ::: "memory"); break;
    case 26: asm volatile("s_waitcnt vmcnt(26)" ::: "memory"); break;
    case 28: asm volatile("s_waitcnt vmcnt(28)" ::: "memory"); break;
    default: asm volatile("s_waitcnt vmcnt(30)" ::: "memory"); break;
  }
}

// ---------------------------------------------------------------------------
// Kernel 1, R4: cast fp32 -> bf16 AND repack into fragment order; sq[i] from
// the ROUNDED values. Same per-thread fmaf chain / reduction tree / stores as
// R0-R3 (bit-identical sq + Xp). NEW: the fp32 source is streamed into a
// 128 KB LDS buffer via coalesced global_load_lds DMA (16 chunks of 8 KB, all
// issued up front = 32 outstanding ops/wave), and each thread reads its
// float4s from LDS. This replaces the old 16-rows-at-8KB-stride gather (16
// cache-line txns per load instr, latency-exposed at 1 wave/SIMD) with pure
// streaming; counted vmcnt(30-2s) lets compute chase the DMA queue.
// LDS swizzle: chunk s, row r, 16B-slot 'slot' holds global unit u=slot^(r&7)
// (linear DMA dest + inverse-swizzled SOURCE + swizzled READ, rule #21) ->
// b128 reads spread uniformly over bank quads (conflict-free floor).
// ---------------------------------------------------------------------------
__global__ __launch_bounds__(256) void prep_kernel(
    const float* __restrict__ X, unsigned short* __restrict__ Xp,
    float* __restrict__ sq, unsigned* __restrict__ ap, unsigned* __restrict__ an)
{
  __shared__ __align__(16) float chunkf[16][2048];   // 16 x 8 KB = 128 KB
  const int b = blockIdx.x;
  const int t = threadIdx.x;
  const int r = t & 15, j = (t >> 4) & 3, w = t >> 6;

  // Stage ALL 16 chunks: chunk s = bytes [s*512, s*512+512) of each of the
  // 16 rows. 512 units of 16 B per chunk; unit v: row rr=v>>5, slot=v&31,
  // global unit u = slot ^ (rr&7). Dest linear in v -> legal gld_lds.
  const char* Xb = (const char*)(X + (size_t)b * 16 * N_DIM);
#pragma unroll
  for (int s = 0; s < 16; ++s) {
#pragma unroll
    for (int q = 0; q < 2; ++q) {
      const unsigned v = q * 256 + t;
      const unsigned rr = v >> 5, slot = v & 31, u = slot ^ (rr & 7);
      gld_lds16(Xb + (size_t)rr * 8192 + s * 512 + u * 16, &chunkf[s][v * 4]);
    }
  }
  __builtin_amdgcn_sched_barrier(0);   // pin all 32 DMA issues above the waits

  unsigned short* Op = Xp + (size_t)b * 64 * 512 + (size_t)(j * 16 + r) * 8;
  const unsigned u0 = (unsigned)(w * 8 + j * 2);
  const unsigned sl0 = (r * 32 + (u0 ^ (r & 7))) * 4;        // float index
  const unsigned sl1 = (r * 32 + ((u0 + 1) ^ (r & 7))) * 4;

  float acc = 0.f;
#pragma unroll
  for (int s = 0; s < 16; ++s) {
    wait_vmcnt_even(30 - 2 * s);       // chunk s's 2 ops retired (in-order)
    __builtin_amdgcn_sched_barrier(0);
    const int c = w + s * 4;
    float4 v0 = *(const float4*)&chunkf[s][sl0];
    float4 v1 = *(const float4*)&chunkf[s][sl1];
    short8 o;
    o[0] = (short)f2bf_rne(v0.x); o[1] = (short)f2bf_rne(v0.y);
    o[2] = (short)f2bf_rne(v0.z); o[3] = (short)f2bf_rne(v0.w);
    o[4] = (short)f2bf_rne(v1.x); o[5] = (short)f2bf_rne(v1.y);
    o[6] = (short)f2bf_rne(v1.z); o[7] = (short)f2bf_rne(v1.w);
#pragma unroll
    for (int e = 0; e < 8; ++e) {
      float f = bf2f((unsigned short)o[e]);
      acc = fmaf(f, f, acc);
    }
    *(short8*)(Op + (size_t)c * 512) = o;
  }
  acc += __shfl_xor(acc, 16, 64);
  acc += __shfl_xor(acc, 32, 64);
  __shared__ float part[4][16];
  if ((t & 63) < 16) part[w][r] = acc;
  __syncthreads();
  if (t < 16) {
    float s4 = part[0][t] + part[1][t] + part[2][t] + part[3][t];
    sq[b * 16 + t] = s4;
    ap[b * 16 + t] = 0u;           // max identity (dist >= 0)
    an[b * 16 + t] = 0x7f7fffffu;  // FLT_MAX bits
  }
}

// ---------------------------------------------------------------------------
// Kernel 2 (UNCHANGED from R3): 64x128 tiles, 1x4 wave grid, A via gld_lds
// double-buffer, B direct-from-global register prefetch, one barrier/iter.
// ---------------------------------------------------------------------------
__global__ __launch_bounds__(256, 4) void dist_kernel(
    const unsigned short* __restrict__ Xp, const float* __restrict__ sq,
    const int* __restrict__ lab, unsigned* __restrict__ ap, unsigned* __restrict__ an)
{
  __shared__ __align__(16) unsigned short As[2][4096];   // 2 x 8 KB (64 rows x 64 k)
  __shared__ float sqi[64], sqj[128];
  __shared__ int labi[64], labj[128];

  // decode linear block id -> (bi, bj) with bj >= bi/2
  int p = blockIdx.x;
  int bi = 0;
  while (p >= NBJ - (bi >> 1)) { p -= NBJ - (bi >> 1); ++bi; }
  const int bj = (bi >> 1) + p;

  const int t = threadIdx.x;
  const int lane = t & 63, w = t >> 6;     // 4 waves, 1x4 grid: wave w owns
                                           // cols [w*32, w*32+32), all 64 rows

  if (t < 64)       { int rr = bi * 64 + t;         sqi[t] = sq[rr];        labi[t] = lab[rr]; }
  else if (t < 192) { int cc = bj * 128 + (t - 64); sqj[t - 64] = sq[cc];   labj[t - 64] = lab[cc]; }

  // A staging: identity chunk map, 512 x 16B units (2/thread). unit u: group
  // gg = u>>7 (wave-uniform), off = u&127 (lane-contiguous) -> legal gld_lds.
  unsigned gA[2], loA[2];
#pragma unroll
  for (int q = 0; q < 2; ++q) {
    const unsigned u = q * 256 + t;
    gA[q] = ((unsigned)(bi * 4 + (u >> 7)) * 64) * 512 + (u & 127) * 8;
    loA[q] = u * 8;
  }
  // B direct: wave w's col 16-groups are (w*2) and (w*2+1). Fragment for
  // (ni, it, kh) at Bb[ni] + it*1024 + kh*512 (shorts), per-lane 16 B.
  const unsigned short* Bb[2];
#pragma unroll
  for (int ni = 0; ni < 2; ++ni)
    Bb[ni] = Xp + ((size_t)(unsigned)(bj * 8 + w * 2 + ni) * 64) * 512 + (unsigned)lane * 8;

#define STAGE_A(BUF, IT)                                                     \
  do {                                                                       \
    _Pragma("unroll")                                                        \
    for (int q = 0; q < 2; ++q)                                              \
      gld_lds16(Xp + gA[q] + (unsigned)(IT) * 1024u, &As[BUF][loA[q]]);      \
  } while (0)

  short8 bc[2][2], bn[2][2];
  STAGE_A(0, 0);
#pragma unroll
  for (int ni = 0; ni < 2; ++ni)
#pragma unroll
    for (int kh = 0; kh < 2; ++kh)
      bc[ni][kh] = *(const short8*)(Bb[ni] + kh * 512);
  __syncthreads();                         // A(0) drained + sqi/sqj visible

  floatx4 acc[4][2] = {};

  for (int it = 0; it < NITER; ++it) {
    const int cur = it & 1;
    const bool has_next = (it + 1 < NITER);
    if (has_next) {
      STAGE_A(cur ^ 1, it + 1);            // async DMA into other buffer
#pragma unroll
      for (int ni = 0; ni < 2; ++ni)
#pragma unroll
        for (int kh = 0; kh < 2; ++kh)
          bn[ni][kh] = *(const short8*)(Bb[ni] + (unsigned)(it + 1) * 1024u + kh * 512);
    }

#pragma unroll
    for (int kh = 0; kh < 2; ++kh) {
      short8 af[4];
#pragma unroll
      for (int mi = 0; mi < 4; ++mi)
        af[mi] = *(const short8*)&As[cur][(mi * 2 + kh) * 512 + lane * 8];
#pragma unroll
      for (int mi = 0; mi < 4; ++mi)
#pragma unroll
        for (int ni = 0; ni < 2; ++ni)
          acc[mi][ni] = __builtin_amdgcn_mfma_f32_16x16x32_bf16(
              af[mi], bc[ni][kh], acc[mi][ni], 0, 0, 0);
    }

    // ONE barrier per iter: all waves' As[cur] reads done (safe to overwrite
    // next iter) AND the implicit vmcnt(0) drains the DMA into As[cur^1].
    __syncthreads();
    if (has_next) {
#pragma unroll
      for (int ni = 0; ni < 2; ++ni)
#pragma unroll
        for (int kh = 0; kh < 2; ++kh)
          bc[ni][kh] = bn[ni][kh];
    }
  }
#undef STAGE_A

  // Epilogue. C/D layout (m89): col = lane&15, row = (lane>>4)*4 + reg.
  const int cn = lane & 15, lg = lane >> 4;
  float sqc[2]; int labc[2];
#pragma unroll
  for (int ni = 0; ni < 2; ++ni) {
    int c = w * 32 + ni * 16 + cn;
    sqc[ni] = sqj[c]; labc[ni] = labj[c];
  }
  float cap[2] = {0.f, 0.f};
  float can[2] = {FLTMAX, FLTMAX};
#pragma unroll
  for (int mi = 0; mi < 4; ++mi) {
#pragma unroll
    for (int r = 0; r < 4; ++r) {
      const int rl = mi * 16 + lg * 4 + r;   // row within 64-tile
      const float si = sqi[rl];
      const int li = labi[rl];
      float apv = 0.0f;
      float anv = FLTMAX;
#pragma unroll
      for (int ni = 0; ni < 2; ++ni) {
        float g = acc[mi][ni][r];
        float d2 = fmaf(-2.0f, g, si + sqc[ni]);
        d2 = fmaxf(d2, 1e-12f);
        float d = __builtin_amdgcn_sqrtf(d2);
        const bool same = (li == labc[ni]);
        const float dp = same ? d : 0.0f;
        const float dn = same ? FLTMAX : d;
        apv = fmaxf(apv, dp);
        anv = fminf(anv, dn);
        cap[ni] = fmaxf(cap[ni], dp);   // col-side (symmetric) partials
        can[ni] = fminf(can[ni], dn);
      }
      // row side: reduce over the 16 cn-lanes (same lg = same row)
#pragma unroll
      for (int m = 8; m >= 1; m >>= 1) {
        apv = fmaxf(apv, __shfl_xor(apv, m, 64));
        anv = fminf(anv, __shfl_xor(anv, m, 64));
      }
      if (cn == 0) {
        int R = bi * 64 + rl;
        atomicMax(&ap[R], __float_as_uint(apv));
        atomicMin(&an[R], __float_as_uint(anv));
      }
    }
  }
  // col side: reduce over lg (xor 16,32) -> full 64 rows per column
#pragma unroll
  for (int ni = 0; ni < 2; ++ni) {
    float a = cap[ni], b = can[ni];
#pragma unroll
    for (int m = 16; m <= 32; m <<= 1) {
      a = fmaxf(a, __shfl_xor(a, m, 64));
      b = fminf(b, __shfl_xor(b, m, 64));
    }
    if (lg == 0) {
      int C = bj * 128 + w * 32 + ni * 16 + cn;
      atomicMax(&ap[C], __float_as_uint(a));
      atomicMin(&an[C], __float_as_uint(b));
    }
  }
}

// ---------------------------------------------------------------------------
// Kernel 3: loss = mean(relu(margin + dist_ap - dist_an)). R4: loads hoisted
// (same i-ascending accumulation order -> bit-identical).
// ---------------------------------------------------------------------------
__global__ __launch_bounds__(256) void finalize_kernel(
    const unsigned* __restrict__ ap, const unsigned* __restrict__ an,
    float* __restrict__ out)
{
  const int t = threadIdx.x;
  float av[16], bv[16];
#pragma unroll
  for (int q = 0; q < 16; ++q) {
    av[q] = __uint_as_float(ap[t + q * 256]);
    bv[q] = __uint_as_float(an[t + q * 256]);
  }
  float s = 0.f;
#pragma unroll
  for (int q = 0; q < 16; ++q) s += fmaxf(MARGIN + av[q] - bv[q], 0.0f);
#pragma unroll
  for (int m = 32; m >= 1; m >>= 1) s += __shfl_down(s, m, 64);
  __shared__ float wsum[4];
  const int lane = t & 63, w = t >> 6;
  if (lane == 0) wsum[w] = s;
  __syncthreads();
  if (t == 0) out[0] = (wsum[0] + wsum[1] + wsum[2] + wsum[3]) * (1.0f / N_ROWS);
}

extern "C" void kernel_launch(void* const* d_in, const int* in_sizes, int n_in,
                              void* d_out, int out_size, void* d_ws, size_t ws_size,
                              hipStream_t stream) {
  const float* X = (const float*)d_in[0];
  const int* lab = (const int*)d_in[1];
  float* out = (float*)d_out;

  char* ws = (char*)d_ws;
  unsigned short* Xp = (unsigned short*)ws;                           // 16 MB packed
  float* sq  = (float*)(ws + (size_t)N_ROWS * N_DIM * 2);             // 16 KB
  unsigned* ap = (unsigned*)((char*)sq + N_ROWS * sizeof(float));     // 16 KB
  unsigned* an = (unsigned*)((char*)ap + N_ROWS * sizeof(unsigned));  // 16 KB

  prep_kernel<<<N_ROWS / 16, 256, 0, stream>>>(X, Xp, sq, ap, an);
  dist_kernel<<<NBLOCKS, 256, 0, stream>>>(Xp, sq, lab, ap, an);
  finalize_kernel<<<1, 256, 0, stream>>>(ap, an, out);
}